// Round 14
// baseline (97.821 us; speedup 1.0000x reference)
//
#include <hip/hip_runtime.h>

// Gaussian VQ forward. Single-pass bf16 MFMA, BARRIER-FREE K-loop: B read
// directly from global (L1/L2-hot codebook), no LDS staging of B at all.
// Scoring, epilogue, merge, tail, gather are VERBATIM R13 (validated,
// absmax 3.2). bs=64, dim_z=64, W=H=32 -> N=65536 rows, K=1024, D=64.
//
// ws layout (bytes):
//   [0    ..  511] : 64 (kld_discrete, kld_continuous) partial pairs (float)
//   [512  .. 4607] : cnorm[1024] fp32
//   [4608 .. 8703] : counts[1024] uint
//   [8704 ..     ] : cb_hi bf16[1024][64]  (131072 B)
#define WS_CNORM_B  512
#define WS_COUNTS_B 4608
#define WS_CBHI_B   8704
#define WS_ZERO_B   8704

typedef __attribute__((ext_vector_type(8))) short short8;
typedef __attribute__((ext_vector_type(4))) float f32x4;

__device__ __forceinline__ unsigned short f2bf(float x) {
  unsigned u = __builtin_bit_cast(unsigned, x);
  u += 0x7fffu + ((u >> 16) & 1u);
  return (unsigned short)(u >> 16);
}
__device__ __forceinline__ int qw(int r, int d) {
  return (r << 6) | (d ^ (r & 31));
}

// ---- prep: codebook -> bf16 + exact ||c||^2 ----
__global__ __launch_bounds__(256) void vq_prep(const float* __restrict__ cb,
                                               char* __restrict__ ws) {
  int tid = blockIdx.x * 256 + threadIdx.x;
  int k = tid >> 6;
  float v = cb[tid];
  ((unsigned short*)(ws + WS_CBHI_B))[tid] = f2bf(v);
  float s = v * v;
  #pragma unroll
  for (int o = 32; o > 0; o >>= 1) s += __shfl_down(s, o);
  if ((threadIdx.x & 63) == 0) ((float*)(ws + WS_CNORM_B))[k] = s;
}

// LDS (bytes):
//   [0, 8192)       z bf16 staging (swizzled [p][d]) — K-loop doesn't touch LDS
//   [0, 16384)      fp32 gather buffer (epilogue, after barriers)
//   [16384, 17664)  row state: 64 x {m, S1, S2, b1, b2} (20 B)
//   [17664, 17920)  fidx[64]
#define ST_OFF   16384
#define FIDX_OFF 17664

__global__ __launch_bounds__(256, 4) void vq_main(const float* __restrict__ z,
                                                  const float* __restrict__ cb,
                                                  const float* __restrict__ var_q,
                                                  char* __restrict__ ws,
                                                  float* __restrict__ out) {
  __shared__ __align__(16) char smem[17920];

  const int t = threadIdx.x;
  const int b = blockIdx.x;          // 1024 blocks, 64 rows each
  const int bb = b >> 4, p0 = (b & 15) << 6;
  const int l = t & 63, wv = t >> 6;           // 4 waves
  const int lg = l >> 4, lr = l & 15;
  const float w = 0.5f / fmaxf(var_q[0], 1e-10f);
  const float w2 = 2.f * w;
  const float nw = -w;

  // ---- stage z (64 rows) -> bf16 at [0,8192), swizzled [p][d] ----
  for (int i = 0; i < 8; ++i) {
    int idx = t + i * 256;             // 2048 u32 slots: p(64) x d2(32)
    int d2 = idx >> 6, p = idx & 63;
    float v0 = z[bb * 65536 + (2 * d2) * 1024 + p0 + p];
    float v1 = z[bb * 65536 + (2 * d2 + 1) * 1024 + p0 + p];
    unsigned short h0 = f2bf(v0), h1 = f2bf(v1);
    int byte = (p * 128 + d2 * 4) ^ ((p & 7) << 4);
    *(unsigned*)(smem + byte) = ((unsigned)h1 << 16) | h0;
  }
  __syncthreads();

  // ---- A fragments: wave's 16 rows (row = wv*16 + lr) ----
  short8 a_hi[2];
  {
    int row = wv * 16 + lr;
    #pragma unroll
    for (int ks = 0; ks < 2; ++ks) {
      int byte = (row * 128 + ks * 64 + lg * 16) ^ ((row & 7) << 4);
      a_hi[ks] = *(const short8*)(smem + byte);
    }
  }
  // no barrier needed until LDS is reused (state write / gather) — the
  // K-loop below touches no LDS.

  // per-lane state: 4 rows (row = wv*16 + lg*4 + j).
  // b1/b2 PACKED (R10-validated): low 10 mantissa bits cleared, code OR'd in.
  float m[4], S1[4], S2[4], b1[4], b2[4];
  #pragma unroll
  for (int j = 0; j < 4; ++j) {
    m[j] = -1e30f; S1[j] = 0.f; S2[j] = 0.f; b1[j] = -1e30f; b2[j] = -1e30f;
  }

  const float* cnf = (const float*)(ws + WS_CNORM_B);
  // per-lane B base: code (ch*64 + ct*16 + lr), k-slice ks, bytes lg*16
  const char* bp = ws + WS_CBHI_B + lr * 128 + lg * 16;

  // ---- BARRIER-FREE K-loop: 16 chunks x 64 codes, B direct from L2 ----
  #pragma unroll 2
  for (int ch = 0; ch < 16; ++ch) {
    short8 bv[4][2];
    #pragma unroll
    for (int ct = 0; ct < 4; ++ct)
      #pragma unroll
      for (int ks = 0; ks < 2; ++ks)
        bv[ct][ks] = *(const short8*)(bp + ch * 8192 + ct * 2048 + ks * 64);

    float cn2[4];
    #pragma unroll
    for (int ct = 0; ct < 4; ++ct) cn2[ct] = nw * cnf[ch * 64 + ct * 16 + lr];

    f32x4 acc[4];
    #pragma unroll
    for (int ct = 0; ct < 4; ++ct) {
      f32x4 a = {};
      a = __builtin_amdgcn_mfma_f32_16x16x32_bf16(a_hi[0], bv[ct][0], a, 0, 0, 0);
      a = __builtin_amdgcn_mfma_f32_16x16x32_bf16(a_hi[1], bv[ct][1], a, 0, 0, 0);
      acc[ct] = a;
    }

    // epilogue: online-max rescale + packed fmax top-2 (verbatim R13)
    #pragma unroll
    for (int j = 0; j < 4; ++j) {
      float lv[4];
      #pragma unroll
      for (int ct = 0; ct < 4; ++ct) lv[ct] = fmaf(acc[ct][j], w2, cn2[ct]);
      float lm = fmaxf(fmaxf(lv[0], lv[1]), fmaxf(lv[2], lv[3]));
      float mn = fmaxf(m[j], lm);
      float sc = __expf(m[j] - mn);
      S1[j] *= sc; S2[j] *= sc; m[j] = mn;
      #pragma unroll
      for (int ct = 0; ct < 4; ++ct) {
        float x = lv[ct];
        unsigned ku = (unsigned)(ch * 64 + ct * 16 + lr);
        unsigned xb = (__builtin_bit_cast(unsigned, x) & ~1023u) | ku;
        float xp = __builtin_bit_cast(float, xb);
        float tm = fminf(b1[j], xp);
        b1[j] = fmaxf(b1[j], xp);
        b2[j] = fmaxf(b2[j], tm);
        float e = __expf(x - mn);
        S1[j] += e;
        S2[j] = fmaf(x, e, S2[j]);   // S2 = sum x * e^{x-m}
      }
    }
  }

  // ---- merge the 16 code-columns within each wave (verbatim R13) ----
  #pragma unroll
  for (int st = 1; st < 16; st <<= 1) {
    #pragma unroll
    for (int j = 0; j < 4; ++j) {
      float om = __shfl_xor(m[j], st);
      float o1 = __shfl_xor(S1[j], st);
      float o2 = __shfl_xor(S2[j], st);
      float ov1 = __shfl_xor(b1[j], st);
      float ov2 = __shfl_xor(b2[j], st);
      float mn = fmaxf(m[j], om);
      float sa = __expf(m[j] - mn), sb = __expf(om - mn);
      S1[j] = sa * S1[j] + sb * o1;
      S2[j] = sa * S2[j] + sb * o2;
      m[j] = mn;
      float nb1 = fmaxf(b1[j], ov1);
      float nb2 = fmaxf(fminf(b1[j], ov1), fmaxf(b2[j], ov2));
      b1[j] = nb1; b2[j] = nb2;
    }
  }

  // ---- state write: 64 rows x 20 B (verbatim R13) ----
  float* stw = (float*)(smem + ST_OFF);
  if (lr == 0) {
    #pragma unroll
    for (int j = 0; j < 4; ++j) {
      int r = wv * 16 + lg * 4 + j;
      float* p = stw + r * 5;
      p[0] = m[j]; p[1] = S1[j]; p[2] = S2[j]; p[3] = b1[j]; p[4] = b2[j];
    }
  }
  __syncthreads();

  // ---- per-row tail (wave 0): entropy + exact fp32 top-2 rescore ----
  int* fidx = (int*)(smem + FIDX_OFF);
  float rowent = 0.f, d2min = 0.f;
  if (t < 64) {
    const float* p = stw + t * 5;
    float mn = p[0], s1 = p[1], s2 = p[2];
    int ka = (int)(__builtin_bit_cast(unsigned, p[3]) & 1023u);
    int kb = (int)(__builtin_bit_cast(unsigned, p[4]) & 1023u);
    rowent = (s2 - mn * s1) / s1 - __logf(s1);
    const float* zp = z + bb * 65536 + p0 + t;
    const float* c1p = cb + ka * 64;
    const float* c2p = cb + kb * 64;
    float zn = 0.f, d1 = 0.f, d2 = 0.f;
    #pragma unroll 4
    for (int d4 = 0; d4 < 16; ++d4) {
      f32x4 ca = *(const f32x4*)(c1p + d4 * 4);
      f32x4 cc = *(const f32x4*)(c2p + d4 * 4);
      #pragma unroll
      for (int e = 0; e < 4; ++e) {
        float v = zp[(d4 * 4 + e) * 1024];
        zn = fmaf(v, v, zn);
        d1 = fmaf(v, ca[e], d1);
        d2 = fmaf(v, cc[e], d2);
      }
    }
    float da = zn + cnf[ka] - 2.f * d1;
    float db = zn + cnf[kb] - 2.f * d2;
    int kwin; float dwin;
    if (da < db || (da == db && ka < kb)) { kwin = ka; dwin = da; }
    else { kwin = kb; dwin = db; }
    fidx[t] = kwin;
    d2min = dwin;
    atomicAdd((unsigned*)(ws + WS_COUNTS_B) + kwin, 1u);
  }
  #pragma unroll
  for (int o = 32; o > 0; o >>= 1) {
    rowent += __shfl_down(rowent, o);
    d2min += __shfl_down(d2min, o);
  }
  if (t == 0) {
    float* wsf = (float*)ws;
    int slot = b & 63;
    atomicAdd(&wsf[slot * 2], rowent);
    atomicAdd(&wsf[slot * 2 + 1], d2min);
  }
  __syncthreads();

  // ---- gather chosen codes via LDS (fp32), write transposed coalesced ----
  float* zl = (float*)smem;  // [0,16384) free now
  for (int i = 0; i < 16; ++i) {
    int idx = t + i * 256;
    int r = idx >> 6, d = idx & 63;
    zl[qw(r, d)] = cb[fidx[r] * 64 + d];
  }
  __syncthreads();
  float* outz = out + bb * 65536 + p0;
  #pragma unroll
  for (int i = 0; i < 4; ++i) {
    int q = t + i * 256;
    int d = q >> 4, rq = q & 15, r = rq << 2;
    f32x4 v;
    v.x = zl[qw(r + 0, d)];
    v.y = zl[qw(r + 1, d)];
    v.z = zl[qw(r + 2, d)];
    v.w = zl[qw(r + 3, d)];
    *(f32x4*)&outz[d * 1024 + r] = v;
  }
}

__global__ __launch_bounds__(1024) void vq_finalize(const float* __restrict__ var_q,
                                                    char* __restrict__ ws,
                                                    float* __restrict__ out) {
  __shared__ float red[48];
  int t = threadIdx.x;
  const unsigned* counts = (const unsigned*)(ws + WS_COUNTS_B);
  const float* wsf = (const float*)ws;
  float avg = (float)counts[t] * (1.0f / 65536.0f);
  float term = avg * __logf(avg + 1e-7f);
  float pd = 0.f, pc = 0.f;
  if (t < 64) { pd = wsf[2 * t]; pc = wsf[2 * t + 1]; }
  #pragma unroll
  for (int o = 32; o > 0; o >>= 1) {
    term += __shfl_down(term, o);
    pd += __shfl_down(pd, o);
    pc += __shfl_down(pc, o);
  }
  int wv = t >> 6, lane = t & 63;
  if (lane == 0) { red[wv * 3] = term; red[wv * 3 + 1] = pd; red[wv * 3 + 2] = pc; }
  __syncthreads();
  if (t == 0) {
    float ts = 0.f, ps = 0.f, cs = 0.f;
    #pragma unroll
    for (int i = 0; i < 16; ++i) {
      ts += red[i * 3]; ps += red[i * 3 + 1]; cs += red[i * 3 + 2];
    }
    float w = 0.5f / fmaxf(var_q[0], 1e-10f);
    out[4194304] = ps / 64.f + w * cs / 64.f;
    out[4194305] = __expf(-ts);
  }
}

extern "C" void kernel_launch(void* const* d_in, const int* in_sizes, int n_in,
                              void* d_out, int out_size, void* d_ws, size_t ws_size,
                              hipStream_t stream) {
  const float* z = (const float*)d_in[0];
  const float* vq = (const float*)d_in[1];
  const float* cb = (const float*)d_in[2];
  float* out = (float*)d_out;
  char* ws = (char*)d_ws;

  hipMemsetAsync(d_ws, 0, WS_ZERO_B, stream);
  vq_prep<<<256, 256, 0, stream>>>(cb, ws);
  vq_main<<<1024, 256, 0, stream>>>(z, cb, vq, ws, out);
  vq_finalize<<<1, 1024, 0, stream>>>(vq, ws, out);
}

// Round 15
// 80.798 us; speedup vs baseline: 1.2107x; 1.2107x over previous
//
#include <hip/hip_runtime.h>

// Gaussian VQ forward. Single-pass bf16 MFMA; codebook LDS-RESIDENT (staged
// once, 128 KB), K-loop has ZERO barriers and zero staging: ds_read->MFMA->
// epilogue only. One 1024-thread block per CU (grid=256), 256 rows/block.
// Scoring/epilogue/merge/tail/gather VERBATIM R13 (validated, absmax 3.2).
// bs=64, dim_z=64, W=H=32 -> N=65536 rows, K=1024 codes, D=64.
//
// ws layout (bytes):
//   [0    ..  511] : 64 (kld_discrete, kld_continuous) partial pairs (float)
//   [512  .. 4607] : cnorm[1024] fp32
//   [4608 .. 8703] : counts[1024] uint
//   [8704 ..     ] : cb_hi bf16[1024][64]  (131072 B)
#define WS_CNORM_B  512
#define WS_COUNTS_B 4608
#define WS_CBHI_B   8704
#define WS_ZERO_B   8704

typedef __attribute__((ext_vector_type(8))) short short8;
typedef __attribute__((ext_vector_type(4))) float f32x4;

__device__ __forceinline__ unsigned short f2bf(float x) {
  unsigned u = __builtin_bit_cast(unsigned, x);
  u += 0x7fffu + ((u >> 16) & 1u);
  return (unsigned short)(u >> 16);
}
__device__ __forceinline__ int qw(int r, int d) {
  return (r << 6) | (d ^ (r & 31));
}

// ---- prep: codebook -> bf16 + exact ||c||^2 (verbatim R14) ----
__global__ __launch_bounds__(256) void vq_prep(const float* __restrict__ cb,
                                               char* __restrict__ ws) {
  int tid = blockIdx.x * 256 + threadIdx.x;
  int k = tid >> 6;
  float v = cb[tid];
  ((unsigned short*)(ws + WS_CBHI_B))[tid] = f2bf(v);
  float s = v * v;
  #pragma unroll
  for (int o = 32; o > 0; o >>= 1) s += __shfl_down(s, o);
  if ((threadIdx.x & 63) == 0) ((float*)(ws + WS_CNORM_B))[k] = s;
}

// LDS (bytes):
//   [0, 131072)     cb bf16 [1024 codes][64 d], XOR-swizzled (staged once).
//                   Prologue first uses [0, 32768) for z bf16 staging.
//                   Epilogue reuses [0, 65536) as fp32 gather buffer.
//   [131072, 136192) row state: 256 x {m, S1, S2, b1, b2} (20 B)
//   [136192, 137216) fidx[256]
#define ST_OFF   131072
#define FIDX_OFF 136192

__global__ __launch_bounds__(1024, 1) void vq_main(const float* __restrict__ z,
                                                   const float* __restrict__ cb,
                                                   const float* __restrict__ var_q,
                                                   char* __restrict__ ws,
                                                   float* __restrict__ out) {
  __shared__ __align__(16) char smem[137216];

  const int t = threadIdx.x;
  const int b = blockIdx.x;          // 256 blocks, 256 rows each
  const int bb = b >> 2, p0 = (b & 3) << 8;
  const int l = t & 63, wv = t >> 6;           // 16 waves
  const int lg = l >> 4, lr = l & 15;
  const float w = 0.5f / fmaxf(var_q[0], 1e-10f);
  const float w2 = 2.f * w;
  const float nw = -w;

  // ---- stage z (256 rows) -> bf16 at [0,32768), swizzled [p][d] ----
  for (int i = 0; i < 8; ++i) {
    int idx = t + i * 1024;            // 8192 u32 slots: p(256) x d2(32)
    int d2 = idx >> 8, p = idx & 255;
    float v0 = z[bb * 65536 + (2 * d2) * 1024 + p0 + p];
    float v1 = z[bb * 65536 + (2 * d2 + 1) * 1024 + p0 + p];
    unsigned short h0 = f2bf(v0), h1 = f2bf(v1);
    int byte = (p * 128 + d2 * 4) ^ ((p & 7) << 4);
    *(unsigned*)(smem + byte) = ((unsigned)h1 << 16) | h0;
  }
  __syncthreads();

  // ---- A fragments: wave's 16 rows (row = wv*16 + lr) ----
  short8 a_hi[2];
  {
    int row = wv * 16 + lr;
    #pragma unroll
    for (int ks = 0; ks < 2; ++ks) {
      int byte = (row * 128 + ks * 64 + lg * 16) ^ ((row & 7) << 4);
      a_hi[ks] = *(const short8*)(smem + byte);
    }
  }
  __syncthreads();  // all z reads done before cb overwrites the region

  // ---- stage ENTIRE codebook (128 KB) into LDS once, swizzled ----
  const char* cbh = ws + WS_CBHI_B;
  #pragma unroll
  for (int pas = 0; pas < 8; ++pas) {
    int o = t + pas * 1024;            // 8192 x 16B units
    int dst = (o * 16) ^ (((o >> 3) & 7) << 4);
    *(f32x4*)(smem + dst) = *(const f32x4*)(cbh + o * 16);
  }
  __syncthreads();   // last barrier before the K-loop

  // per-lane state: 4 rows (row = wv*16 + lg*4 + j).
  // b1/b2 PACKED (R10-validated): low 10 mantissa bits cleared, code OR'd in.
  float m[4], S1[4], S2[4], b1[4], b2[4];
  #pragma unroll
  for (int j = 0; j < 4; ++j) {
    m[j] = -1e30f; S1[j] = 0.f; S2[j] = 0.f; b1[j] = -1e30f; b2[j] = -1e30f;
  }

  const float* cnf = (const float*)(ws + WS_CNORM_B);

  // ---- BARRIER-FREE K-loop: 16 chunks x 64 codes, B from resident LDS ----
  for (int ch = 0; ch < 16; ++ch) {
    float cn2[4];
    #pragma unroll
    for (int ct = 0; ct < 4; ++ct) cn2[ct] = nw * cnf[ch * 64 + ct * 16 + lr];

    f32x4 acc[4];
    #pragma unroll
    for (int ct = 0; ct < 4; ++ct) {
      int k = ch * 64 + ct * 16 + lr;
      f32x4 a = {};
      #pragma unroll
      for (int ks = 0; ks < 2; ++ks) {
        int byte = (k * 128 + ks * 64 + lg * 16) ^ ((k & 7) << 4);
        short8 bh = *(const short8*)(smem + byte);
        a = __builtin_amdgcn_mfma_f32_16x16x32_bf16(a_hi[ks], bh, a, 0, 0, 0);
      }
      acc[ct] = a;
    }

    // epilogue: online-max rescale + packed fmax top-2 (verbatim R13)
    #pragma unroll
    for (int j = 0; j < 4; ++j) {
      float lv[4];
      #pragma unroll
      for (int ct = 0; ct < 4; ++ct) lv[ct] = fmaf(acc[ct][j], w2, cn2[ct]);
      float lm = fmaxf(fmaxf(lv[0], lv[1]), fmaxf(lv[2], lv[3]));
      float mn = fmaxf(m[j], lm);
      float sc = __expf(m[j] - mn);
      S1[j] *= sc; S2[j] *= sc; m[j] = mn;
      #pragma unroll
      for (int ct = 0; ct < 4; ++ct) {
        float x = lv[ct];
        unsigned ku = (unsigned)(ch * 64 + ct * 16 + lr);
        unsigned xb = (__builtin_bit_cast(unsigned, x) & ~1023u) | ku;
        float xp = __builtin_bit_cast(float, xb);
        float tm = fminf(b1[j], xp);
        b1[j] = fmaxf(b1[j], xp);
        b2[j] = fmaxf(b2[j], tm);
        float e = __expf(x - mn);
        S1[j] += e;
        S2[j] = fmaf(x, e, S2[j]);   // S2 = sum x * e^{x-m}
      }
    }
  }

  // ---- merge the 16 code-columns within each wave (verbatim R13) ----
  #pragma unroll
  for (int st = 1; st < 16; st <<= 1) {
    #pragma unroll
    for (int j = 0; j < 4; ++j) {
      float om = __shfl_xor(m[j], st);
      float o1 = __shfl_xor(S1[j], st);
      float o2 = __shfl_xor(S2[j], st);
      float ov1 = __shfl_xor(b1[j], st);
      float ov2 = __shfl_xor(b2[j], st);
      float mn = fmaxf(m[j], om);
      float sa = __expf(m[j] - mn), sb = __expf(om - mn);
      S1[j] = sa * S1[j] + sb * o1;
      S2[j] = sa * S2[j] + sb * o2;
      m[j] = mn;
      float nb1 = fmaxf(b1[j], ov1);
      float nb2 = fmaxf(fminf(b1[j], ov1), fmaxf(b2[j], ov2));
      b1[j] = nb1; b2[j] = nb2;
    }
  }

  // ---- state write: 256 rows x 20 B ----
  float* stw = (float*)(smem + ST_OFF);
  if (lr == 0) {
    #pragma unroll
    for (int j = 0; j < 4; ++j) {
      int r = wv * 16 + lg * 4 + j;
      float* p = stw + r * 5;
      p[0] = m[j]; p[1] = S1[j]; p[2] = S2[j]; p[3] = b1[j]; p[4] = b2[j];
    }
  }
  __syncthreads();

  // ---- per-row tail (waves 0-3): entropy + exact fp32 top-2 rescore ----
  int* fidx = (int*)(smem + FIDX_OFF);
  float rowent = 0.f, d2min = 0.f;
  if (t < 256) {
    const float* p = stw + t * 5;
    float mn = p[0], s1 = p[1], s2 = p[2];
    int ka = (int)(__builtin_bit_cast(unsigned, p[3]) & 1023u);
    int kb = (int)(__builtin_bit_cast(unsigned, p[4]) & 1023u);
    rowent = (s2 - mn * s1) / s1 - __logf(s1);
    const float* zp = z + bb * 65536 + p0 + t;
    const float* c1p = cb + ka * 64;
    const float* c2p = cb + kb * 64;
    float zn = 0.f, d1 = 0.f, d2 = 0.f;
    #pragma unroll 4
    for (int d4 = 0; d4 < 16; ++d4) {
      f32x4 ca = *(const f32x4*)(c1p + d4 * 4);
      f32x4 cc = *(const f32x4*)(c2p + d4 * 4);
      #pragma unroll
      for (int e = 0; e < 4; ++e) {
        float v = zp[(d4 * 4 + e) * 1024];
        zn = fmaf(v, v, zn);
        d1 = fmaf(v, ca[e], d1);
        d2 = fmaf(v, cc[e], d2);
      }
    }
    float da = zn + cnf[ka] - 2.f * d1;
    float db = zn + cnf[kb] - 2.f * d2;
    int kwin; float dwin;
    if (da < db || (da == db && ka < kb)) { kwin = ka; dwin = da; }
    else { kwin = kb; dwin = db; }
    fidx[t] = kwin;
    d2min = dwin;
    atomicAdd((unsigned*)(ws + WS_COUNTS_B) + kwin, 1u);
  }
  #pragma unroll
  for (int o = 32; o > 0; o >>= 1) {
    rowent += __shfl_down(rowent, o);
    d2min += __shfl_down(d2min, o);
  }
  if (t < 256 && l == 0) {   // lane 0 of waves 0-3
    float* wsf = (float*)ws;
    int slot = (b * 4 + wv) & 63;
    atomicAdd(&wsf[slot * 2], rowent);
    atomicAdd(&wsf[slot * 2 + 1], d2min);
  }
  __syncthreads();

  // ---- gather chosen codes via LDS (fp32), write transposed coalesced ----
  float* zl = (float*)smem;  // cb region dead now; 64 KB used
  for (int i = 0; i < 16; ++i) {
    int idx = t + i * 1024;            // 16384 floats: r(256) x d(64)
    int r = idx >> 6, d = idx & 63;
    zl[qw(r, d)] = cb[fidx[r] * 64 + d];
  }
  __syncthreads();
  float* outz = out + bb * 65536 + p0;
  #pragma unroll
  for (int i = 0; i < 4; ++i) {
    int q = t + i * 1024;              // 4096 f32x4 stores
    int d = q >> 6, rq = q & 63, r = rq << 2;
    f32x4 v;
    v.x = zl[qw(r + 0, d)];
    v.y = zl[qw(r + 1, d)];
    v.z = zl[qw(r + 2, d)];
    v.w = zl[qw(r + 3, d)];
    *(f32x4*)&outz[d * 1024 + r] = v;
  }
}

__global__ __launch_bounds__(1024) void vq_finalize(const float* __restrict__ var_q,
                                                    char* __restrict__ ws,
                                                    float* __restrict__ out) {
  __shared__ float red[48];
  int t = threadIdx.x;
  const unsigned* counts = (const unsigned*)(ws + WS_COUNTS_B);
  const float* wsf = (const float*)ws;
  float avg = (float)counts[t] * (1.0f / 65536.0f);
  float term = avg * __logf(avg + 1e-7f);
  float pd = 0.f, pc = 0.f;
  if (t < 64) { pd = wsf[2 * t]; pc = wsf[2 * t + 1]; }
  #pragma unroll
  for (int o = 32; o > 0; o >>= 1) {
    term += __shfl_down(term, o);
    pd += __shfl_down(pd, o);
    pc += __shfl_down(pc, o);
  }
  int wv = t >> 6, lane = t & 63;
  if (lane == 0) { red[wv * 3] = term; red[wv * 3 + 1] = pd; red[wv * 3 + 2] = pc; }
  __syncthreads();
  if (t == 0) {
    float ts = 0.f, ps = 0.f, cs = 0.f;
    #pragma unroll
    for (int i = 0; i < 16; ++i) {
      ts += red[i * 3]; ps += red[i * 3 + 1]; cs += red[i * 3 + 2];
    }
    float w = 0.5f / fmaxf(var_q[0], 1e-10f);
    out[4194304] = ps / 64.f + w * cs / 64.f;
    out[4194305] = __expf(-ts);
  }
}

extern "C" void kernel_launch(void* const* d_in, const int* in_sizes, int n_in,
                              void* d_out, int out_size, void* d_ws, size_t ws_size,
                              hipStream_t stream) {
  const float* z = (const float*)d_in[0];
  const float* vq = (const float*)d_in[1];
  const float* cb = (const float*)d_in[2];
  float* out = (float*)d_out;
  char* ws = (char*)d_ws;

  hipMemsetAsync(d_ws, 0, WS_ZERO_B, stream);
  vq_prep<<<256, 256, 0, stream>>>(cb, ws);
  vq_main<<<256, 1024, 0, stream>>>(z, cb, vq, ws, out);
  vq_finalize<<<1, 1024, 0, stream>>>(vq, ws, out);
}

// Round 17
// 60.800 us; speedup vs baseline: 1.6089x; 1.3289x over previous
//
#include <hip/hip_runtime.h>

// Gaussian VQ forward. R13 (validated 66.8us, absmax 3.23) with ONLY the
// dead cb_lo/z_lo/a_lo staging deleted. HARD INVARIANT from the R12/R16
// bisection: packed top-2 + exact fp32 rescore of BOTH candidates stays
// (top-1-direct failed identically twice; top-2+rescore passed twice).
// bs=64, dim_z=64, W=H=32 -> N=65536 rows, K=1024 codes, D=64.
//
// ws layout (bytes):
//   [0    ..  511] : 64 (kld_discrete, kld_continuous) partial pairs (float)
//   [512  .. 4607] : cnorm[1024] fp32 (exact)
//   [4608 .. 8703] : counts[1024] uint
//   [8704 ..     ] : cb_hi bf16[1024][64]  (131072 B)
#define WS_CNORM_B  512
#define WS_COUNTS_B 4608
#define WS_CBHI_B   8704
#define WS_ZERO_B   8704

typedef __attribute__((ext_vector_type(8))) short short8;
typedef __attribute__((ext_vector_type(4))) float f32x4;

__device__ __forceinline__ unsigned short f2bf(float x) {
  unsigned u = __builtin_bit_cast(unsigned, x);
  u += 0x7fffu + ((u >> 16) & 1u);
  return (unsigned short)(u >> 16);
}
__device__ __forceinline__ int qw(int r, int d) {
  return (r << 6) | (d ^ (r & 31));
}

// ---- prep: codebook -> bf16 + exact ||c||^2 (verbatim R16) ----
__global__ __launch_bounds__(256) void vq_prep(const float* __restrict__ cb,
                                               char* __restrict__ ws) {
  int tid = blockIdx.x * 256 + threadIdx.x;
  int k = tid >> 6;
  float v = cb[tid];
  ((unsigned short*)(ws + WS_CBHI_B))[tid] = f2bf(v);
  float s = v * v;
  #pragma unroll
  for (int o = 32; o > 0; o >>= 1) s += __shfl_down(s, o);
  if ((threadIdx.x & 63) == 0) ((float*)(ws + WS_CNORM_B))[k] = s;
}

// LDS (bytes):
//   [0, 16384)      chunk dbuf: parity p at [p*8192, +8192) (64 codes bf16,
//                   swizzled). Prologue: z bf16 staging at [0, 8192).
//                   Epilogue: fp32 gather buffer [0, 16384).
//   [16384, 17664)  row state: 64 x {m, S1, S2, b1, b2} (20 B, scalar stores)
//   [17664, 17920)  fidx[64]
#define ST_OFF   16384
#define FIDX_OFF 17664

__global__ __launch_bounds__(256, 4) void vq_main(const float* __restrict__ z,
                                                  const float* __restrict__ cb,
                                                  const float* __restrict__ var_q,
                                                  char* __restrict__ ws,
                                                  float* __restrict__ out) {
  __shared__ __align__(16) char smem[17920];

  const int t = threadIdx.x;
  const int b = blockIdx.x;          // 1024 blocks, 64 rows each
  const int bb = b >> 4, p0 = (b & 15) << 6;
  const int l = t & 63, wv = t >> 6;           // 4 waves
  const int lg = l >> 4, lr = l & 15;
  const float w = 0.5f / fmaxf(var_q[0], 1e-10f);
  const float w2 = 2.f * w;
  const float nw = -w;

  // ---- stage z (64 rows) -> bf16 at [0,8192), swizzled [p][d] ----
  for (int i = 0; i < 8; ++i) {
    int idx = t + i * 256;             // 2048 u32 slots: p(64) x d2(32)
    int d2 = idx >> 6, p = idx & 63;
    float v0 = z[bb * 65536 + (2 * d2) * 1024 + p0 + p];
    float v1 = z[bb * 65536 + (2 * d2 + 1) * 1024 + p0 + p];
    unsigned short h0 = f2bf(v0), h1 = f2bf(v1);
    int byte = (p * 128 + d2 * 4) ^ ((p & 7) << 4);
    *(unsigned*)(smem + byte) = ((unsigned)h1 << 16) | h0;
  }
  __syncthreads();

  // ---- A fragments: wave's 16 rows (row = wv*16 + lr) ----
  short8 a_hi[2];
  {
    int row = wv * 16 + lr;
    #pragma unroll
    for (int ks = 0; ks < 2; ++ks) {
      int byte = (row * 128 + ks * 64 + lg * 16) ^ ((row & 7) << 4);
      a_hi[ks] = *(const short8*)(smem + byte);
    }
  }
  __syncthreads();  // z reads done; region becomes chunk dbuf

  // ---- prologue: stage chunk 0 (64 codes bf16 = 8KB) into parity 0 ----
  const char* cbh = ws + WS_CBHI_B;
  {
    #pragma unroll
    for (int pas = 0; pas < 2; ++pas) {
      int o = t + pas * 256;           // o in [0,512): 16B units
      int dst = (o * 16) ^ (((o >> 3) & 7) << 4);
      *(f32x4*)(smem + dst) = *(const f32x4*)(cbh + o * 16);
    }
  }
  __syncthreads();

  // per-lane state: 4 rows (row = wv*16 + lg*4 + j).
  // b1/b2 PACKED (validated R10/R11/R13): low 10 mantissa bits cleared,
  // code OR'd in; exact fp32 rescore of BOTH candidates arbitrates.
  float m[4], S1[4], S2[4], b1[4], b2[4];
  #pragma unroll
  for (int j = 0; j < 4; ++j) {
    m[j] = -1e30f; S1[j] = 0.f; S2[j] = 0.f; b1[j] = -1e30f; b2[j] = -1e30f;
  }

  const float* cnf = (const float*)(ws + WS_CNORM_B);

  for (int ch = 0; ch < 16; ++ch) {
    char* cur = smem + (ch & 1) * 8192;
    char* nxt = smem + ((ch + 1) & 1) * 8192;
    f32x4 rh0, rh1;
    const bool pf = ch < 15;
    if (pf) {  // prefetch next chunk into regs; latency hides under compute
      const char* sh = cbh + (ch + 1) * 8192 + t * 16;
      rh0 = *(const f32x4*)sh;
      rh1 = *(const f32x4*)(sh + 4096);
    }
    float cn2[4];
    #pragma unroll
    for (int ct = 0; ct < 4; ++ct) cn2[ct] = nw * cnf[ch * 64 + ct * 16 + lr];

    f32x4 acc[4];
    #pragma unroll
    for (int ct = 0; ct < 4; ++ct) {
      f32x4 a = {};
      #pragma unroll
      for (int ks = 0; ks < 2; ++ks) {
        int cr = ct * 16 + lr;
        int byte = (cr * 128 + ks * 64 + lg * 16) ^ ((cr & 7) << 4);
        short8 bh = *(const short8*)(cur + byte);
        a = __builtin_amdgcn_mfma_f32_16x16x32_bf16(a_hi[ks], bh, a, 0, 0, 0);
      }
      acc[ct] = a;
    }

    // epilogue: online-max rescale + packed fmax top-2 (VERBATIM R13)
    #pragma unroll
    for (int j = 0; j < 4; ++j) {
      float lv[4];
      #pragma unroll
      for (int ct = 0; ct < 4; ++ct) lv[ct] = fmaf(acc[ct][j], w2, cn2[ct]);
      float lm = fmaxf(fmaxf(lv[0], lv[1]), fmaxf(lv[2], lv[3]));
      float mn = fmaxf(m[j], lm);
      float sc = __expf(m[j] - mn);
      S1[j] *= sc; S2[j] *= sc; m[j] = mn;
      #pragma unroll
      for (int ct = 0; ct < 4; ++ct) {
        float x = lv[ct];
        unsigned ku = (unsigned)(ch * 64 + ct * 16 + lr);
        unsigned xb = (__builtin_bit_cast(unsigned, x) & ~1023u) | ku;
        float xp = __builtin_bit_cast(float, xb);
        float tm = fminf(b1[j], xp);
        b1[j] = fmaxf(b1[j], xp);
        b2[j] = fmaxf(b2[j], tm);
        float e = __expf(x - mn);
        S1[j] += e;
        S2[j] = fmaf(x, e, S2[j]);   // S2 = sum x * e^{x-m}
      }
    }

    if (pf) {
      #pragma unroll
      for (int pas = 0; pas < 2; ++pas) {
        int o = t + pas * 256;
        int dst = (o * 16) ^ (((o >> 3) & 7) << 4);
        *(f32x4*)(nxt + dst) = pas ? rh1 : rh0;
      }
    }
    __syncthreads();
  }

  // ---- merge the 16 code-columns within each wave (VERBATIM R13) ----
  #pragma unroll
  for (int st = 1; st < 16; st <<= 1) {
    #pragma unroll
    for (int j = 0; j < 4; ++j) {
      float om = __shfl_xor(m[j], st);
      float o1 = __shfl_xor(S1[j], st);
      float o2 = __shfl_xor(S2[j], st);
      float ov1 = __shfl_xor(b1[j], st);
      float ov2 = __shfl_xor(b2[j], st);
      float mn = fmaxf(m[j], om);
      float sa = __expf(m[j] - mn), sb = __expf(om - mn);
      S1[j] = sa * S1[j] + sb * o1;
      S2[j] = sa * S2[j] + sb * o2;
      m[j] = mn;
      float nb1 = fmaxf(b1[j], ov1);
      float nb2 = fmaxf(fminf(b1[j], ov1), fmaxf(b2[j], ov2));
      b1[j] = nb1; b2[j] = nb2;
    }
  }

  // ---- state write: 64 rows x 20 B scalar stores (VERBATIM R13) ----
  float* stw = (float*)(smem + ST_OFF);
  if (lr == 0) {
    #pragma unroll
    for (int j = 0; j < 4; ++j) {
      int r = wv * 16 + lg * 4 + j;
      float* p = stw + r * 5;
      p[0] = m[j]; p[1] = S1[j]; p[2] = S2[j]; p[3] = b1[j]; p[4] = b2[j];
    }
  }
  __syncthreads();

  // ---- per-row tail (wave 0): entropy + exact fp32 top-2 rescore ----
  int* fidx = (int*)(smem + FIDX_OFF);
  float rowent = 0.f, d2min = 0.f;
  if (t < 64) {
    const float* p = stw + t * 5;
    float mn = p[0], s1 = p[1], s2 = p[2];
    int ka = (int)(__builtin_bit_cast(unsigned, p[3]) & 1023u);
    int kb = (int)(__builtin_bit_cast(unsigned, p[4]) & 1023u);
    rowent = (s2 - mn * s1) / s1 - __logf(s1);
    const float* zp = z + bb * 65536 + p0 + t;
    const float* c1p = cb + ka * 64;
    const float* c2p = cb + kb * 64;
    float zn = 0.f, d1 = 0.f, d2 = 0.f;
    #pragma unroll 4
    for (int d4 = 0; d4 < 16; ++d4) {
      f32x4 ca = *(const f32x4*)(c1p + d4 * 4);
      f32x4 cc = *(const f32x4*)(c2p + d4 * 4);
      #pragma unroll
      for (int e = 0; e < 4; ++e) {
        float v = zp[(d4 * 4 + e) * 1024];
        zn = fmaf(v, v, zn);
        d1 = fmaf(v, ca[e], d1);
        d2 = fmaf(v, cc[e], d2);
      }
    }
    float da = zn + cnf[ka] - 2.f * d1;
    float db = zn + cnf[kb] - 2.f * d2;
    int kwin; float dwin;
    if (da < db || (da == db && ka < kb)) { kwin = ka; dwin = da; }
    else { kwin = kb; dwin = db; }
    fidx[t] = kwin;
    d2min = dwin;
    atomicAdd((unsigned*)(ws + WS_COUNTS_B) + kwin, 1u);
  }
  #pragma unroll
  for (int o = 32; o > 0; o >>= 1) {
    rowent += __shfl_down(rowent, o);
    d2min += __shfl_down(d2min, o);
  }
  if (t == 0) {
    float* wsf = (float*)ws;
    int slot = b & 63;
    atomicAdd(&wsf[slot * 2], rowent);
    atomicAdd(&wsf[slot * 2 + 1], d2min);
  }
  __syncthreads();

  // ---- gather chosen codes via LDS (fp32), write transposed coalesced ----
  float* zl = (float*)smem;  // dbuf region dead now (4096 words used)
  for (int i = 0; i < 16; ++i) {
    int idx = t + i * 256;
    int r = idx >> 6, d = idx & 63;
    zl[qw(r, d)] = cb[fidx[r] * 64 + d];
  }
  __syncthreads();
  float* outz = out + bb * 65536 + p0;
  #pragma unroll
  for (int i = 0; i < 4; ++i) {
    int q = t + i * 256;
    int d = q >> 4, rq = q & 15, r = rq << 2;
    f32x4 v;
    v.x = zl[qw(r + 0, d)];
    v.y = zl[qw(r + 1, d)];
    v.z = zl[qw(r + 2, d)];
    v.w = zl[qw(r + 3, d)];
    *(f32x4*)&outz[d * 1024 + r] = v;
  }
}

__global__ __launch_bounds__(1024) void vq_finalize(const float* __restrict__ var_q,
                                                    char* __restrict__ ws,
                                                    float* __restrict__ out) {
  __shared__ float red[48];
  int t = threadIdx.x;
  const unsigned* counts = (const unsigned*)(ws + WS_COUNTS_B);
  const float* wsf = (const float*)ws;
  float avg = (float)counts[t] * (1.0f / 65536.0f);
  float term = avg * __logf(avg + 1e-7f);
  float pd = 0.f, pc = 0.f;
  if (t < 64) { pd = wsf[2 * t]; pc = wsf[2 * t + 1]; }
  #pragma unroll
  for (int o = 32; o > 0; o >>= 1) {
    term += __shfl_down(term, o);
    pd += __shfl_down(pd, o);
    pc += __shfl_down(pc, o);
  }
  int wv = t >> 6, lane = t & 63;
  if (lane == 0) { red[wv * 3] = term; red[wv * 3 + 1] = pd; red[wv * 3 + 2] = pc; }
  __syncthreads();
  if (t == 0) {
    float ts = 0.f, ps = 0.f, cs = 0.f;
    #pragma unroll
    for (int i = 0; i < 16; ++i) {
      ts += red[i * 3]; ps += red[i * 3 + 1]; cs += red[i * 3 + 2];
    }
    float w = 0.5f / fmaxf(var_q[0], 1e-10f);
    out[4194304] = ps / 64.f + w * cs / 64.f;
    out[4194305] = __expf(-ts);
  }
}

extern "C" void kernel_launch(void* const* d_in, const int* in_sizes, int n_in,
                              void* d_out, int out_size, void* d_ws, size_t ws_size,
                              hipStream_t stream) {
  const float* z = (const float*)d_in[0];
  const float* vq = (const float*)d_in[1];
  const float* cb = (const float*)d_in[2];
  float* out = (float*)d_out;
  char* ws = (char*)d_ws;

  hipMemsetAsync(d_ws, 0, WS_ZERO_B, stream);
  vq_prep<<<256, 256, 0, stream>>>(cb, ws);
  vq_main<<<1024, 256, 0, stream>>>(z, cb, vq, ws, out);
  vq_finalize<<<1, 1024, 0, stream>>>(vq, ws, out);
}